// Round 10
// baseline (80.222 us; speedup 1.0000x reference)
//
#include <hip/hip_runtime.h>
#include <hip/hip_bf16.h>
#include <float.h>

typedef unsigned short u16;
typedef unsigned long long u64;
typedef __attribute__((ext_vector_type(8))) short short8;  // 8 bf16 in 4 VGPRs
typedef __attribute__((ext_vector_type(4))) float f32x4;

#define NB       4
#define LQ       4096
#define LKV      512
#define DMODEL   512
#define NH       8
#define DH       64
#define KW       9
#define SCALE    0.125f

#define BM 64
#define BN 64
#define BK 64

__device__ inline float bf2f(u16 v) { return __uint_as_float(((unsigned)v) << 16); }
// hardware packed fp32->bf16 (RNE), 2 elems / instruction
__device__ inline unsigned pk2(float a, float b) {
    unsigned r;
    asm("v_cvt_pk_bf16_f32 %0, %1, %2" : "=v"(r) : "v"(a), "v"(b));
    return r;
}
__device__ inline u16 f2bf(float f) {               // scalar fallback (transpose kernel)
    unsigned u = __float_as_uint(f);
    return (u16)((u + 0x7fffu + ((u >> 16) & 1u)) >> 16);
}
__device__ inline void gload16(const u16* g, u16* l) {
    __builtin_amdgcn_global_load_lds((const __attribute__((address_space(1))) void*)g,
                                     (__attribute__((address_space(3))) void*)l, 16, 0, 0);
}
__device__ inline short8 cvt8(const float4 v0, const float4 v1) {
    union { unsigned u[4]; short8 s; } r;
    r.u[0] = pk2(v0.x, v0.y);
    r.u[1] = pk2(v0.z, v0.w);
    r.u[2] = pk2(v1.x, v1.y);
    r.u[3] = pk2(v1.z, v1.w);
    return r.s;
}
// XCD-chunked bijective swizzle (nwg % 8 == 0)
__device__ inline int xcd_swz(int id, int nwg) {
    const int cpx = nwg >> 3;
    return (id & 7) * cpx + (id >> 3);
}

// ---------------------------------------------------------------------------
// all 4 weight transposes in one launch
// ---------------------------------------------------------------------------
__global__ __launch_bounds__(256) void transpose4_kernel(
    const float* __restrict__ Wq, const float* __restrict__ Wk,
    const float* __restrict__ Wv, const float* __restrict__ Wo,
    u16* __restrict__ Wqt, u16* __restrict__ Wkvt, u16* __restrict__ Wot)
{
    __shared__ float tile[32][33];
    const int z = blockIdx.z;
    const float* src = (z == 0) ? Wq : (z == 1) ? Wk : (z == 2) ? Wv : Wo;
    u16* dst = (z == 0) ? Wqt : (z == 3) ? Wot : Wkvt;
    const int roff = (z == 2) ? DMODEL : 0;

    const int tx = threadIdx.x & 31, ty = threadIdx.x >> 5;   // 32x8
    const int x0 = blockIdx.x * 32, y0 = blockIdx.y * 32;
    #pragma unroll
    for (int i = 0; i < 4; ++i)
        tile[ty + i * 8][tx] = src[(y0 + ty + i * 8) * DMODEL + x0 + tx];
    __syncthreads();
    #pragma unroll
    for (int i = 0; i < 4; ++i)
        dst[(long long)(roff + x0 + ty + i * 8) * DMODEL + y0 + tx] = f2bf(tile[tx][ty + i * 8]);
}

// ---------------------------------------------------------------------------
// bf16 MFMA GEMM, 64x64 tile, BK=64, 4 waves (each 32x32, acc[2][2]).
// 1D grid, XCD-chunked swizzle, cshift=log2(N/BN).
// A_F32: fp32 A reg-staged (+prefetch) -> bf16 LDS. OUT_F32: fp32 out + mask.
// PACK_MASK: block 0 additionally packs kv_mask into a bitmask in mbits.
// ---------------------------------------------------------------------------
template<int A_F32, int OUT_F32, int PACK_MASK>
__global__ __launch_bounds__(256, 8) void gemm64_kernel(
    const void* __restrict__ Ain, const u16* __restrict__ Bt,
    const float* __restrict__ bias0, const float* __restrict__ bias1, int nsplit,
    void* __restrict__ Cout, int N, int K, int cshift,
    const unsigned char* __restrict__ row_mask,
    const unsigned char* __restrict__ kv_mask_in, u64* __restrict__ mbits_out)
{
    __shared__ u16 As[BM * BK];   // 8 KB
    __shared__ u16 Bs[BN * BK];   // 8 KB

    const int tid = threadIdx.x;
    const int w = tid >> 6, l = tid & 63;
    const int wr = w >> 1, wc = w & 1;

    if (PACK_MASK) {
        if (blockIdx.x == 0 && tid < 36) {
            if (tid < 32) {
                const int b = tid >> 3, wd = tid & 7;
                const unsigned char* p = kv_mask_in + b * LKV + wd * 64;
                u64 m = 0;
                for (int i = 0; i < 64; ++i) m |= ((u64)(p[i] != 0)) << i;
                mbits_out[b * 9 + wd] = m;
            } else {
                mbits_out[(tid - 32) * 9 + 8] = 0ULL;
            }
        }
    }

    const int wg = xcd_swz((int)blockIdx.x, (int)gridDim.x);
    const int bx = wg & ((1 << cshift) - 1);
    const int by = wg >> cshift;
    const int brow = by * BM, bcol = bx * BN;

    const int srow   = l >> 3;                 // row within 8-row group
    const int schunk = ((l & 7) ^ srow) * 8;   // pre-swizzled source k-offset
    const long long ar0 = brow + w * 16 + srow;
    const long long br0 = bcol + w * 16 + srow;
    const u16*   gA0  = (const u16*)Ain   + ar0 * K + schunk;
    const u16*   gA1  = gA0 + 8 * K;
    const float* gAf0 = (const float*)Ain + ar0 * K + schunk;
    const float* gAf1 = gAf0 + 8 * K;
    const u16* gB0 = Bt + br0 * K + schunk;
    const u16* gB1 = gB0 + 8 * K;
    u16* lA0 = As + (w * 16) * BK;
    u16* lA1 = As + (w * 16 + 8) * BK;
    u16* lB0 = Bs + (w * 16) * BK;
    u16* lB1 = Bs + (w * 16 + 8) * BK;

    const int hi = l >> 4, lr = l & 15;
    const int r7 = lr & 7;

    f32x4 acc[2][2] = {};

    float4 p0, p1, p2, p3;
    if (A_F32) {
        p0 = *(const float4*)(gAf0);     p1 = *(const float4*)(gAf0 + 4);
        p2 = *(const float4*)(gAf1);     p3 = *(const float4*)(gAf1 + 4);
    }

    for (int k0 = 0; k0 < K; k0 += BK) {
        if (A_F32) {
            *(short8*)(lA0 + l * 8) = cvt8(p0, p1);
            *(short8*)(lA1 + l * 8) = cvt8(p2, p3);
        } else {
            gload16(gA0 + k0, lA0);
            gload16(gA1 + k0, lA1);
        }
        gload16(gB0 + k0, lB0);
        gload16(gB1 + k0, lB1);
        __syncthreads();

        if (A_F32 && k0 + BK < K) {       // prefetch next iter under MFMA
            p0 = *(const float4*)(gAf0 + k0 + BK); p1 = *(const float4*)(gAf0 + k0 + BK + 4);
            p2 = *(const float4*)(gAf1 + k0 + BK); p3 = *(const float4*)(gAf1 + k0 + BK + 4);
        }

        #pragma unroll
        for (int g2 = 0; g2 < 2; ++g2) {
            const int slot = ((g2 * 4 + hi) ^ r7) * 8;
            short8 a[2], b[2];
            #pragma unroll
            for (int m = 0; m < 2; ++m)
                a[m] = *(const short8*)&As[(wr * 32 + m * 16 + lr) * BK + slot];
            #pragma unroll
            for (int n = 0; n < 2; ++n)
                b[n] = *(const short8*)&Bs[(wc * 32 + n * 16 + lr) * BK + slot];
            #pragma unroll
            for (int m = 0; m < 2; ++m)
                #pragma unroll
                for (int n = 0; n < 2; ++n)
                    acc[m][n] = __builtin_amdgcn_mfma_f32_16x16x32_bf16(a[m], b[n], acc[m][n], 0, 0, 0);
        }
        __syncthreads();
    }

    #pragma unroll
    for (int m = 0; m < 2; ++m) {
        #pragma unroll
        for (int n = 0; n < 2; ++n) {
            const int col = bcol + wc * 32 + n * 16 + lr;
            const float bv = (col < nsplit) ? bias0[col] : bias1[col - nsplit];
            const int row0 = brow + wr * 32 + m * 16 + hi * 4;
            if (OUT_F32) {
                #pragma unroll
                for (int r = 0; r < 4; ++r) {
                    const int row = row0 + r;
                    const float v = acc[m][n][r] + bv;
                    ((float*)Cout)[(long long)row * N + col] =
                        (row_mask != nullptr && row_mask[row]) ? 0.0f : v;
                }
            } else {
                const unsigned pa = pk2(acc[m][n][0] + bv, acc[m][n][1] + bv);
                const unsigned pb = pk2(acc[m][n][2] + bv, acc[m][n][3] + bv);
                u16* cp = (u16*)Cout + (long long)row0 * N + col;
                cp[0]           = (u16)pa;
                cp[(long long)N]     = (u16)(pa >> 16);
                cp[(long long)2 * N] = (u16)pb;
                cp[(long long)3 * N] = (u16)(pb >> 16);
            }
        }
    }
}

// ---------------------------------------------------------------------------
// FUSED Q-projection (64 rows x 1 head) + windowed attention.
// qt[64][64] aliases As (dead after final barrier).
// Attention: 8 lanes/item, 2 passes; per pass ALL 9 K loads issued first
// (batched, independent), grouped shfl tree, softmax, ALL 9 V loads batched.
// __launch_bounds__(256,6): ~85 VGPRs so the load batches stay in flight.
// ---------------------------------------------------------------------------
__global__ __launch_bounds__(256, 6) void qproj_attn_kernel(
    const float* __restrict__ Aq, const u16* __restrict__ Bt,
    const float* __restrict__ bias, const u16* __restrict__ khv,
    const int* __restrict__ seg_id, const u64* __restrict__ mbits,
    u16* __restrict__ atb)
{
    __shared__ u16 smem[BM * BK + BN * BK];   // 16 KB
    u16* As = smem;
    u16* Bs = smem + BM * BK;
    u16* qt = smem;                            // 8 KB, reused after k-loop

    const int tid = threadIdx.x;
    const int w = tid >> 6, l = tid & 63;
    const int wr = w >> 1, wc = w & 1;

    const int wg = xcd_swz((int)blockIdx.x, (int)gridDim.x);
    const int bx = wg & 7;                     // 8 col blocks = 8 heads
    const int by = wg >> 3;
    const int brow = by * BM, bcol = bx * BN;
    const int K = DMODEL;
    const int head = bx;

    const int srow   = l >> 3;
    const int schunk = ((l & 7) ^ srow) * 8;
    const long long ar0 = brow + w * 16 + srow;
    const long long br0 = bcol + w * 16 + srow;
    const float* gAf0 = Aq + ar0 * K + schunk;
    const float* gAf1 = gAf0 + 8 * K;
    const u16* gB0 = Bt + br0 * K + schunk;
    const u16* gB1 = gB0 + 8 * K;
    u16* lA0 = As + (w * 16) * BK;
    u16* lA1 = As + (w * 16 + 8) * BK;
    u16* lB0 = Bs + (w * 16) * BK;
    u16* lB1 = Bs + (w * 16 + 8) * BK;

    const int hi = l >> 4, lr = l & 15;
    const int r7 = lr & 7;

    f32x4 acc[2][2] = {};

    float4 p0 = *(const float4*)(gAf0), p1 = *(const float4*)(gAf0 + 4);
    float4 p2 = *(const float4*)(gAf1), p3 = *(const float4*)(gAf1 + 4);

    for (int k0 = 0; k0 < K; k0 += BK) {
        *(short8*)(lA0 + l * 8) = cvt8(p0, p1);
        *(short8*)(lA1 + l * 8) = cvt8(p2, p3);
        gload16(gB0 + k0, lB0);
        gload16(gB1 + k0, lB1);
        __syncthreads();

        if (k0 + BK < K) {
            p0 = *(const float4*)(gAf0 + k0 + BK); p1 = *(const float4*)(gAf0 + k0 + BK + 4);
            p2 = *(const float4*)(gAf1 + k0 + BK); p3 = *(const float4*)(gAf1 + k0 + BK + 4);
        }

        #pragma unroll
        for (int g2 = 0; g2 < 2; ++g2) {
            const int slot = ((g2 * 4 + hi) ^ r7) * 8;
            short8 a[2], b[2];
            #pragma unroll
            for (int m = 0; m < 2; ++m)
                a[m] = *(const short8*)&As[(wr * 32 + m * 16 + lr) * BK + slot];
            #pragma unroll
            for (int n = 0; n < 2; ++n)
                b[n] = *(const short8*)&Bs[(wc * 32 + n * 16 + lr) * BK + slot];
            #pragma unroll
            for (int m = 0; m < 2; ++m)
                #pragma unroll
                for (int n = 0; n < 2; ++n)
                    acc[m][n] = __builtin_amdgcn_mfma_f32_16x16x32_bf16(a[m], b[n], acc[m][n], 0, 0, 0);
        }
        __syncthreads();                       // last As/Bs reads complete
    }

    // ---- qt stash (aliases As) ----
    #pragma unroll
    for (int m = 0; m < 2; ++m) {
        #pragma unroll
        for (int n = 0; n < 2; ++n) {
            const int col = wc * 32 + n * 16 + lr;
            const float bv = bias[bcol + col];
            const int row0 = wr * 32 + m * 16 + hi * 4;
            const unsigned pa = pk2(acc[m][n][0] + bv, acc[m][n][1] + bv);
            const unsigned pb = pk2(acc[m][n][2] + bv, acc[m][n][3] + bv);
            const int cslot = (col & 7);
            qt[(row0 + 0) * BN + (((col >> 3) ^ ((row0 + 0) & 7)) << 3) + cslot] = (u16)pa;
            qt[(row0 + 1) * BN + (((col >> 3) ^ ((row0 + 1) & 7)) << 3) + cslot] = (u16)(pa >> 16);
            qt[(row0 + 2) * BN + (((col >> 3) ^ ((row0 + 2) & 7)) << 3) + cslot] = (u16)pb;
            qt[(row0 + 3) * BN + (((col >> 3) ^ ((row0 + 3) & 7)) << 3) + cslot] = (u16)(pb >> 16);
        }
    }
    __syncthreads();

    // ---- attention: 8 lanes per item, 2 passes of 32 items ----
    const int dchunk = tid & 7;
    #pragma unroll
    for (int p = 0; p < 2; ++p) {
        const int row = p * 32 + (tid >> 3);      // local row 0..63
        const long long bl = brow + row;
        const int b = (int)(bl >> 12);            // LQ = 2^12
        const int seg = seg_id[bl];
        const u16* kvb = khv + (long long)b * LKV * 1024;

        // mask window: bits for idx in [lo, seg], bit position = idx - lo
        int lo = seg - (KW - 1); if (lo < 0) lo = 0;
        const int w0 = lo >> 6, off = lo & 63;
        const u64* mb = mbits + b * 9;
        u64 wv = mb[w0] >> off;
        if (off) wv |= mb[w0 + 1] << (64 - off);

        const short8 q8 = *(const short8*)&qt[row * BN + ((dchunk ^ (row & 7)) << 3)];
        float qf[8];
        #pragma unroll
        for (int e = 0; e < 8; ++e) qf[e] = bf2f((u16)q8[e]);

        // all window indices
        int idxs[KW];
        #pragma unroll
        for (int j = 0; j < KW; ++j) {
            int idx = seg - j; if (idx < 0) idx = 0;
            idxs[j] = idx;
        }

        // batch ALL K loads (independent, fill MEM pipe)
        short8 k8[KW];
        #pragma unroll
        for (int j = 0; j < KW; ++j)
            k8[j] = *(const short8*)&kvb[(long long)idxs[j] * 1024 + head * DH + dchunk * 8];

        // independent partial dots
        float d[KW];
        #pragma unroll
        for (int j = 0; j < KW; ++j) {
            float d0 = 0.0f, d1 = 0.0f;
            #pragma unroll
            for (int e = 0; e < 8; e += 2) {
                d0 = fmaf(qf[e],     bf2f((u16)k8[j][e]),     d0);
                d1 = fmaf(qf[e + 1], bf2f((u16)k8[j][e + 1]), d1);
            }
            d[j] = d0 + d1;
        }
        // grouped shfl tree: 9 independent swizzles per level, pipelined
        #pragma unroll
        for (int j = 0; j < KW; ++j) d[j] += __shfl_xor(d[j], 1);
        #pragma unroll
        for (int j = 0; j < KW; ++j) d[j] += __shfl_xor(d[j], 2);
        #pragma unroll
        for (int j = 0; j < KW; ++j) d[j] += __shfl_xor(d[j], 4);

        float sc[KW];
        #pragma unroll
        for (int j = 0; j < KW; ++j) {
            float s = d[j] * SCALE;
            if ((wv >> (idxs[j] - lo)) & 1) s = -FLT_MAX;
            sc[j] = s;
        }

        // batch ALL V loads while softmax computes
        short8 v8[KW];
        #pragma unroll
        for (int j = 0; j < KW; ++j)
            v8[j] = *(const short8*)&kvb[(long long)idxs[j] * 1024 + DMODEL + head * DH + dchunk * 8];

        float mx = sc[0];
        #pragma unroll
        for (int j = 1; j < KW; ++j) mx = fmaxf(mx, sc[j]);
        float den = 0.0f;
        #pragma unroll
        for (int j = 0; j < KW; ++j) { sc[j] = __expf(sc[j] - mx); den += sc[j]; }
        const float inv = 1.0f / den;

        float o[8];
        #pragma unroll
        for (int e = 0; e < 8; ++e) o[e] = 0.0f;
        #pragma unroll
        for (int j = 0; j < KW; ++j) {
            const float pj = sc[j];
            #pragma unroll
            for (int e = 0; e < 8; ++e)
                o[e] = fmaf(pj, bf2f((u16)v8[j][e]), o[e]);
        }

        union { unsigned u[4]; short8 s; } ov;
        #pragma unroll
        for (int e = 0; e < 4; ++e)
            ov.u[e] = pk2(o[2 * e] * inv, o[2 * e + 1] * inv);
        *(short8*)&atb[bl * DMODEL + head * DH + dchunk * 8] = ov.s;
    }
}

extern "C" void kernel_launch(void* const* d_in, const int* in_sizes, int n_in,
                              void* d_out, int out_size, void* d_ws, size_t ws_size,
                              hipStream_t stream) {
    const float*         q          = (const float*)d_in[0];
    const float*         kv_src     = (const float*)d_in[1];
    const int*           seg_id     = (const int*)d_in[2];
    const unsigned char* kv_mask    = (const unsigned char*)d_in[3];
    const unsigned char* q_pad_mask = (const unsigned char*)d_in[4];
    const float*         Wq         = (const float*)d_in[5];
    const float*         bq         = (const float*)d_in[6];
    const float*         Wk         = (const float*)d_in[7];
    const float*         bk         = (const float*)d_in[8];
    const float*         Wv         = (const float*)d_in[9];
    const float*         bv         = (const float*)d_in[10];
    const float*         Wo         = (const float*)d_in[11];
    const float*         bo         = (const float*)d_in[12];
    float* out = (float*)d_out;

    const long long MQ  = (long long)NB * LQ;    // 16384
    const long long MKV = (long long)NB * LKV;   // 2048

    char* wsb = (char*)d_ws;
    u16* Wqt  = (u16*)wsb;  wsb += DMODEL * DMODEL * 2;       // 0.5 MB
    u16* Wkvt = (u16*)wsb;  wsb += 2 * DMODEL * DMODEL * 2;   //  1 MB
    u16* Wot  = (u16*)wsb;  wsb += DMODEL * DMODEL * 2;       // 0.5 MB
    u16* khv  = (u16*)wsb;  wsb += MKV * 2 * DMODEL * 2;      //  4 MB
    u16* atb  = (u16*)wsb;  wsb += MQ  * DMODEL * 2;          // 16 MB
    u64* mbits = (u64*)wsb; wsb += NB * 9 * 8;                // 288 B

    dim3 blk(256);

    transpose4_kernel<<<dim3(DMODEL / 32, DMODEL / 32, 4), blk, 0, stream>>>(
        Wq, Wk, Wv, Wo, Wqt, Wkvt, Wot);

    // fused K+V projection (fp32 A) + kv_mask bitpack; 512 blocks, cshift=4
    gemm64_kernel<1, 0, 1><<<dim3((unsigned)((2 * DMODEL / BN) * (MKV / BM))), blk, 0, stream>>>(
        kv_src, Wkvt, bk, bv, DMODEL, khv, 2 * DMODEL, DMODEL, 4, nullptr, kv_mask, mbits);

    // fused Q projection (fp32 A) + windowed attention -> atb; 2048 blocks
    qproj_attn_kernel<<<dim3((unsigned)((DMODEL / BN) * (MQ / BM))), blk, 0, stream>>>(
        q, Wqt, bq, khv, seg_id, mbits, atb);

    // output projection + pad-mask zeroing (fp32 out); 2048 blocks, cshift=3
    gemm64_kernel<0, 1, 0><<<dim3((unsigned)((DMODEL / BN) * (MQ / BM))), blk, 0, stream>>>(
        atb, Wot, bo, bo, DMODEL, out, DMODEL, DMODEL, 3, q_pad_mask, nullptr, nullptr);
}

// Round 11
// 71.561 us; speedup vs baseline: 1.1210x; 1.1210x over previous
//
#include <hip/hip_runtime.h>
#include <hip/hip_bf16.h>
#include <float.h>

typedef unsigned short u16;
typedef unsigned long long u64;
typedef __attribute__((ext_vector_type(8))) short short8;  // 8 bf16 in 4 VGPRs
typedef __attribute__((ext_vector_type(4))) float f32x4;

#define NB       4
#define LQ       4096
#define LKV      512
#define DMODEL   512
#define NH       8
#define DH       64
#define KW       9
#define SCALE    0.125f

#define BM 64
#define BN 64
#define BK 64

__device__ inline float bf2f(u16 v) { return __uint_as_float(((unsigned)v) << 16); }
// hardware packed fp32->bf16 (RNE), 2 elems / instruction
__device__ inline unsigned pk2(float a, float b) {
    unsigned r;
    asm("v_cvt_pk_bf16_f32 %0, %1, %2" : "=v"(r) : "v"(a), "v"(b));
    return r;
}
__device__ inline u16 f2bf(float f) {               // scalar fallback (transpose kernel)
    unsigned u = __float_as_uint(f);
    return (u16)((u + 0x7fffu + ((u >> 16) & 1u)) >> 16);
}
__device__ inline void gload16(const u16* g, u16* l) {
    __builtin_amdgcn_global_load_lds((const __attribute__((address_space(1))) void*)g,
                                     (__attribute__((address_space(3))) void*)l, 16, 0, 0);
}
__device__ inline short8 cvt8(const float4 v0, const float4 v1) {
    union { unsigned u[4]; short8 s; } r;
    r.u[0] = pk2(v0.x, v0.y);
    r.u[1] = pk2(v0.z, v0.w);
    r.u[2] = pk2(v1.x, v1.y);
    r.u[3] = pk2(v1.z, v1.w);
    return r.s;
}
// XCD-chunked bijective swizzle (nwg % 8 == 0)
__device__ inline int xcd_swz(int id, int nwg) {
    const int cpx = nwg >> 3;
    return (id & 7) * cpx + (id >> 3);
}

// ---------------------------------------------------------------------------
// all 4 weight transposes in one launch
// ---------------------------------------------------------------------------
__global__ __launch_bounds__(256) void transpose4_kernel(
    const float* __restrict__ Wq, const float* __restrict__ Wk,
    const float* __restrict__ Wv, const float* __restrict__ Wo,
    u16* __restrict__ Wqt, u16* __restrict__ Wkvt, u16* __restrict__ Wot)
{
    __shared__ float tile[32][33];
    const int z = blockIdx.z;
    const float* src = (z == 0) ? Wq : (z == 1) ? Wk : (z == 2) ? Wv : Wo;
    u16* dst = (z == 0) ? Wqt : (z == 3) ? Wot : Wkvt;
    const int roff = (z == 2) ? DMODEL : 0;

    const int tx = threadIdx.x & 31, ty = threadIdx.x >> 5;   // 32x8
    const int x0 = blockIdx.x * 32, y0 = blockIdx.y * 32;
    #pragma unroll
    for (int i = 0; i < 4; ++i)
        tile[ty + i * 8][tx] = src[(y0 + ty + i * 8) * DMODEL + x0 + tx];
    __syncthreads();
    #pragma unroll
    for (int i = 0; i < 4; ++i)
        dst[(long long)(roff + x0 + ty + i * 8) * DMODEL + y0 + tx] = f2bf(tile[tx][ty + i * 8]);
}

// ---------------------------------------------------------------------------
// bf16 MFMA GEMM, 64x64 tile, BK=64, 4 waves (each 32x32, acc[2][2]).
// 1D grid, XCD-chunked swizzle, cshift=log2(N/BN).
// A_F32: fp32 A reg-staged (+prefetch) -> bf16 LDS. OUT_F32: fp32 out + mask.
// PACK_MASK: block 0 additionally packs kv_mask into a bitmask in mbits.
// ---------------------------------------------------------------------------
template<int A_F32, int OUT_F32, int PACK_MASK>
__global__ __launch_bounds__(256, 8) void gemm64_kernel(
    const void* __restrict__ Ain, const u16* __restrict__ Bt,
    const float* __restrict__ bias0, const float* __restrict__ bias1, int nsplit,
    void* __restrict__ Cout, int N, int K, int cshift,
    const unsigned char* __restrict__ row_mask,
    const unsigned char* __restrict__ kv_mask_in, u64* __restrict__ mbits_out)
{
    __shared__ u16 As[BM * BK];   // 8 KB
    __shared__ u16 Bs[BN * BK];   // 8 KB

    const int tid = threadIdx.x;
    const int w = tid >> 6, l = tid & 63;
    const int wr = w >> 1, wc = w & 1;

    if (PACK_MASK) {
        if (blockIdx.x == 0 && tid < 36) {
            if (tid < 32) {
                const int b = tid >> 3, wd = tid & 7;
                const unsigned char* p = kv_mask_in + b * LKV + wd * 64;
                u64 m = 0;
                for (int i = 0; i < 64; ++i) m |= ((u64)(p[i] != 0)) << i;
                mbits_out[b * 9 + wd] = m;
            } else {
                mbits_out[(tid - 32) * 9 + 8] = 0ULL;
            }
        }
    }

    const int wg = xcd_swz((int)blockIdx.x, (int)gridDim.x);
    const int bx = wg & ((1 << cshift) - 1);
    const int by = wg >> cshift;
    const int brow = by * BM, bcol = bx * BN;

    const int srow   = l >> 3;                 // row within 8-row group
    const int schunk = ((l & 7) ^ srow) * 8;   // pre-swizzled source k-offset
    const long long ar0 = brow + w * 16 + srow;
    const long long br0 = bcol + w * 16 + srow;
    const u16*   gA0  = (const u16*)Ain   + ar0 * K + schunk;
    const u16*   gA1  = gA0 + 8 * K;
    const float* gAf0 = (const float*)Ain + ar0 * K + schunk;
    const float* gAf1 = gAf0 + 8 * K;
    const u16* gB0 = Bt + br0 * K + schunk;
    const u16* gB1 = gB0 + 8 * K;
    u16* lA0 = As + (w * 16) * BK;
    u16* lA1 = As + (w * 16 + 8) * BK;
    u16* lB0 = Bs + (w * 16) * BK;
    u16* lB1 = Bs + (w * 16 + 8) * BK;

    const int hi = l >> 4, lr = l & 15;
    const int r7 = lr & 7;

    f32x4 acc[2][2] = {};

    float4 p0, p1, p2, p3;
    if (A_F32) {
        p0 = *(const float4*)(gAf0);     p1 = *(const float4*)(gAf0 + 4);
        p2 = *(const float4*)(gAf1);     p3 = *(const float4*)(gAf1 + 4);
    }

    for (int k0 = 0; k0 < K; k0 += BK) {
        if (A_F32) {
            *(short8*)(lA0 + l * 8) = cvt8(p0, p1);
            *(short8*)(lA1 + l * 8) = cvt8(p2, p3);
        } else {
            gload16(gA0 + k0, lA0);
            gload16(gA1 + k0, lA1);
        }
        gload16(gB0 + k0, lB0);
        gload16(gB1 + k0, lB1);
        __syncthreads();

        if (A_F32 && k0 + BK < K) {       // prefetch next iter under MFMA
            p0 = *(const float4*)(gAf0 + k0 + BK); p1 = *(const float4*)(gAf0 + k0 + BK + 4);
            p2 = *(const float4*)(gAf1 + k0 + BK); p3 = *(const float4*)(gAf1 + k0 + BK + 4);
        }

        #pragma unroll
        for (int g2 = 0; g2 < 2; ++g2) {
            const int slot = ((g2 * 4 + hi) ^ r7) * 8;
            short8 a[2], b[2];
            #pragma unroll
            for (int m = 0; m < 2; ++m)
                a[m] = *(const short8*)&As[(wr * 32 + m * 16 + lr) * BK + slot];
            #pragma unroll
            for (int n = 0; n < 2; ++n)
                b[n] = *(const short8*)&Bs[(wc * 32 + n * 16 + lr) * BK + slot];
            #pragma unroll
            for (int m = 0; m < 2; ++m)
                #pragma unroll
                for (int n = 0; n < 2; ++n)
                    acc[m][n] = __builtin_amdgcn_mfma_f32_16x16x32_bf16(a[m], b[n], acc[m][n], 0, 0, 0);
        }
        __syncthreads();
    }

    #pragma unroll
    for (int m = 0; m < 2; ++m) {
        #pragma unroll
        for (int n = 0; n < 2; ++n) {
            const int col = bcol + wc * 32 + n * 16 + lr;
            const float bv = (col < nsplit) ? bias0[col] : bias1[col - nsplit];
            const int row0 = brow + wr * 32 + m * 16 + hi * 4;
            if (OUT_F32) {
                #pragma unroll
                for (int r = 0; r < 4; ++r) {
                    const int row = row0 + r;
                    const float v = acc[m][n][r] + bv;
                    ((float*)Cout)[(long long)row * N + col] =
                        (row_mask != nullptr && row_mask[row]) ? 0.0f : v;
                }
            } else {
                const unsigned pa = pk2(acc[m][n][0] + bv, acc[m][n][1] + bv);
                const unsigned pb = pk2(acc[m][n][2] + bv, acc[m][n][3] + bv);
                u16* cp = (u16*)Cout + (long long)row0 * N + col;
                cp[0]           = (u16)pa;
                cp[(long long)N]     = (u16)(pa >> 16);
                cp[(long long)2 * N] = (u16)pb;
                cp[(long long)3 * N] = (u16)(pb >> 16);
            }
        }
    }
}

// ---------------------------------------------------------------------------
// FUSED Q-projection (64 rows x 1 head) + windowed attention.
// qt[64][64] aliases As (dead after final barrier).
// Attention: 8 lanes/item, 2 passes; ALL 9 K loads batched (registers now
// available: __launch_bounds__(256,4) -> 128 VGPR cap, no spill), grouped
// shfl tree, softmax, ALL 9 V loads batched.
// ---------------------------------------------------------------------------
__global__ __launch_bounds__(256, 4) void qproj_attn_kernel(
    const float* __restrict__ Aq, const u16* __restrict__ Bt,
    const float* __restrict__ bias, const u16* __restrict__ khv,
    const int* __restrict__ seg_id, const u64* __restrict__ mbits,
    u16* __restrict__ atb)
{
    __shared__ u16 smem[BM * BK + BN * BK];   // 16 KB
    u16* As = smem;
    u16* Bs = smem + BM * BK;
    u16* qt = smem;                            // 8 KB, reused after k-loop

    const int tid = threadIdx.x;
    const int w = tid >> 6, l = tid & 63;
    const int wr = w >> 1, wc = w & 1;

    const int wg = xcd_swz((int)blockIdx.x, (int)gridDim.x);
    const int bx = wg & 7;                     // 8 col blocks = 8 heads
    const int by = wg >> 3;
    const int brow = by * BM, bcol = bx * BN;
    const int K = DMODEL;
    const int head = bx;

    const int srow   = l >> 3;
    const int schunk = ((l & 7) ^ srow) * 8;
    const long long ar0 = brow + w * 16 + srow;
    const long long br0 = bcol + w * 16 + srow;
    const float* gAf0 = Aq + ar0 * K + schunk;
    const float* gAf1 = gAf0 + 8 * K;
    const u16* gB0 = Bt + br0 * K + schunk;
    const u16* gB1 = gB0 + 8 * K;
    u16* lA0 = As + (w * 16) * BK;
    u16* lA1 = As + (w * 16 + 8) * BK;
    u16* lB0 = Bs + (w * 16) * BK;
    u16* lB1 = Bs + (w * 16 + 8) * BK;

    const int hi = l >> 4, lr = l & 15;
    const int r7 = lr & 7;

    f32x4 acc[2][2] = {};

    float4 p0 = *(const float4*)(gAf0), p1 = *(const float4*)(gAf0 + 4);
    float4 p2 = *(const float4*)(gAf1), p3 = *(const float4*)(gAf1 + 4);

    for (int k0 = 0; k0 < K; k0 += BK) {
        *(short8*)(lA0 + l * 8) = cvt8(p0, p1);
        *(short8*)(lA1 + l * 8) = cvt8(p2, p3);
        gload16(gB0 + k0, lB0);
        gload16(gB1 + k0, lB1);
        __syncthreads();

        if (k0 + BK < K) {
            p0 = *(const float4*)(gAf0 + k0 + BK); p1 = *(const float4*)(gAf0 + k0 + BK + 4);
            p2 = *(const float4*)(gAf1 + k0 + BK); p3 = *(const float4*)(gAf1 + k0 + BK + 4);
        }

        #pragma unroll
        for (int g2 = 0; g2 < 2; ++g2) {
            const int slot = ((g2 * 4 + hi) ^ r7) * 8;
            short8 a[2], b[2];
            #pragma unroll
            for (int m = 0; m < 2; ++m)
                a[m] = *(const short8*)&As[(wr * 32 + m * 16 + lr) * BK + slot];
            #pragma unroll
            for (int n = 0; n < 2; ++n)
                b[n] = *(const short8*)&Bs[(wc * 32 + n * 16 + lr) * BK + slot];
            #pragma unroll
            for (int m = 0; m < 2; ++m)
                #pragma unroll
                for (int n = 0; n < 2; ++n)
                    acc[m][n] = __builtin_amdgcn_mfma_f32_16x16x32_bf16(a[m], b[n], acc[m][n], 0, 0, 0);
        }
        __syncthreads();                       // last As/Bs reads complete
    }

    // ---- qt stash (aliases As) ----
    #pragma unroll
    for (int m = 0; m < 2; ++m) {
        #pragma unroll
        for (int n = 0; n < 2; ++n) {
            const int col = wc * 32 + n * 16 + lr;
            const float bv = bias[bcol + col];
            const int row0 = wr * 32 + m * 16 + hi * 4;
            const unsigned pa = pk2(acc[m][n][0] + bv, acc[m][n][1] + bv);
            const unsigned pb = pk2(acc[m][n][2] + bv, acc[m][n][3] + bv);
            const int cslot = (col & 7);
            qt[(row0 + 0) * BN + (((col >> 3) ^ ((row0 + 0) & 7)) << 3) + cslot] = (u16)pa;
            qt[(row0 + 1) * BN + (((col >> 3) ^ ((row0 + 1) & 7)) << 3) + cslot] = (u16)(pa >> 16);
            qt[(row0 + 2) * BN + (((col >> 3) ^ ((row0 + 2) & 7)) << 3) + cslot] = (u16)pb;
            qt[(row0 + 3) * BN + (((col >> 3) ^ ((row0 + 3) & 7)) << 3) + cslot] = (u16)(pb >> 16);
        }
    }
    __syncthreads();

    // ---- attention: 8 lanes per item, 2 passes of 32 items ----
    const int dchunk = tid & 7;
    #pragma unroll
    for (int p = 0; p < 2; ++p) {
        const int row = p * 32 + (tid >> 3);      // local row 0..63
        const long long bl = brow + row;
        const int b = (int)(bl >> 12);            // LQ = 2^12
        const int seg = seg_id[bl];
        const u16* kvb = khv + (long long)b * LKV * 1024;

        // mask window: bits for idx in [lo, seg], bit position = idx - lo
        int lo = seg - (KW - 1); if (lo < 0) lo = 0;
        const int w0 = lo >> 6, off = lo & 63;
        const u64* mb = mbits + b * 9;
        u64 wv = mb[w0] >> off;
        if (off) wv |= mb[w0 + 1] << (64 - off);

        const short8 q8 = *(const short8*)&qt[row * BN + ((dchunk ^ (row & 7)) << 3)];
        float qf[8];
        #pragma unroll
        for (int e = 0; e < 8; ++e) qf[e] = bf2f((u16)q8[e]);

        // all window indices
        int idxs[KW];
        #pragma unroll
        for (int j = 0; j < KW; ++j) {
            int idx = seg - j; if (idx < 0) idx = 0;
            idxs[j] = idx;
        }

        // batch ALL K loads (independent, fill MEM pipe)
        short8 k8[KW];
        #pragma unroll
        for (int j = 0; j < KW; ++j)
            k8[j] = *(const short8*)&kvb[(long long)idxs[j] * 1024 + head * DH + dchunk * 8];

        // independent partial dots
        float d[KW];
        #pragma unroll
        for (int j = 0; j < KW; ++j) {
            float d0 = 0.0f, d1 = 0.0f;
            #pragma unroll
            for (int e = 0; e < 8; e += 2) {
                d0 = fmaf(qf[e],     bf2f((u16)k8[j][e]),     d0);
                d1 = fmaf(qf[e + 1], bf2f((u16)k8[j][e + 1]), d1);
            }
            d[j] = d0 + d1;
        }
        // grouped shfl tree: 9 independent swizzles per level, pipelined
        #pragma unroll
        for (int j = 0; j < KW; ++j) d[j] += __shfl_xor(d[j], 1);
        #pragma unroll
        for (int j = 0; j < KW; ++j) d[j] += __shfl_xor(d[j], 2);
        #pragma unroll
        for (int j = 0; j < KW; ++j) d[j] += __shfl_xor(d[j], 4);

        float sc[KW];
        #pragma unroll
        for (int j = 0; j < KW; ++j) {
            float s = d[j] * SCALE;
            if ((wv >> (idxs[j] - lo)) & 1) s = -FLT_MAX;
            sc[j] = s;
        }

        // batch ALL V loads while softmax computes
        short8 v8[KW];
        #pragma unroll
        for (int j = 0; j < KW; ++j)
            v8[j] = *(const short8*)&kvb[(long long)idxs[j] * 1024 + DMODEL + head * DH + dchunk * 8];

        float mx = sc[0];
        #pragma unroll
        for (int j = 1; j < KW; ++j) mx = fmaxf(mx, sc[j]);
        float den = 0.0f;
        #pragma unroll
        for (int j = 0; j < KW; ++j) { sc[j] = __expf(sc[j] - mx); den += sc[j]; }
        const float inv = 1.0f / den;

        float o[8];
        #pragma unroll
        for (int e = 0; e < 8; ++e) o[e] = 0.0f;
        #pragma unroll
        for (int j = 0; j < KW; ++j) {
            const float pj = sc[j];
            #pragma unroll
            for (int e = 0; e < 8; ++e)
                o[e] = fmaf(pj, bf2f((u16)v8[j][e]), o[e]);
        }

        union { unsigned u[4]; short8 s; } ov;
        #pragma unroll
        for (int e = 0; e < 4; ++e)
            ov.u[e] = pk2(o[2 * e] * inv, o[2 * e + 1] * inv);
        *(short8*)&atb[bl * DMODEL + head * DH + dchunk * 8] = ov.s;
    }
}

extern "C" void kernel_launch(void* const* d_in, const int* in_sizes, int n_in,
                              void* d_out, int out_size, void* d_ws, size_t ws_size,
                              hipStream_t stream) {
    const float*         q          = (const float*)d_in[0];
    const float*         kv_src     = (const float*)d_in[1];
    const int*           seg_id     = (const int*)d_in[2];
    const unsigned char* kv_mask    = (const unsigned char*)d_in[3];
    const unsigned char* q_pad_mask = (const unsigned char*)d_in[4];
    const float*         Wq         = (const float*)d_in[5];
    const float*         bq         = (const float*)d_in[6];
    const float*         Wk         = (const float*)d_in[7];
    const float*         bk         = (const float*)d_in[8];
    const float*         Wv         = (const float*)d_in[9];
    const float*         bv         = (const float*)d_in[10];
    const float*         Wo         = (const float*)d_in[11];
    const float*         bo         = (const float*)d_in[12];
    float* out = (float*)d_out;

    const long long MQ  = (long long)NB * LQ;    // 16384
    const long long MKV = (long long)NB * LKV;   // 2048

    char* wsb = (char*)d_ws;
    u16* Wqt  = (u16*)wsb;  wsb += DMODEL * DMODEL * 2;       // 0.5 MB
    u16* Wkvt = (u16*)wsb;  wsb += 2 * DMODEL * DMODEL * 2;   //  1 MB
    u16* Wot  = (u16*)wsb;  wsb += DMODEL * DMODEL * 2;       // 0.5 MB
    u16* khv  = (u16*)wsb;  wsb += MKV * 2 * DMODEL * 2;      //  4 MB
    u16* atb  = (u16*)wsb;  wsb += MQ  * DMODEL * 2;          // 16 MB
    u64* mbits = (u64*)wsb; wsb += NB * 9 * 8;                // 288 B

    dim3 blk(256);

    transpose4_kernel<<<dim3(DMODEL / 32, DMODEL / 32, 4), blk, 0, stream>>>(
        Wq, Wk, Wv, Wo, Wqt, Wkvt, Wot);

    // fused K+V projection (fp32 A) + kv_mask bitpack; 512 blocks, cshift=4
    gemm64_kernel<1, 0, 1><<<dim3((unsigned)((2 * DMODEL / BN) * (MKV / BM))), blk, 0, stream>>>(
        kv_src, Wkvt, bk, bv, DMODEL, khv, 2 * DMODEL, DMODEL, 4, nullptr, kv_mask, mbits);

    // fused Q projection (fp32 A) + windowed attention -> atb; 2048 blocks
    qproj_attn_kernel<<<dim3((unsigned)((DMODEL / BN) * (MQ / BM))), blk, 0, stream>>>(
        q, Wqt, bq, khv, seg_id, mbits, atb);

    // output projection + pad-mask zeroing (fp32 out); 2048 blocks, cshift=3
    gemm64_kernel<0, 1, 0><<<dim3((unsigned)((DMODEL / BN) * (MQ / BM))), blk, 0, stream>>>(
        atb, Wot, bo, bo, DMODEL, out, DMODEL, DMODEL, 3, q_pad_mask, nullptr, nullptr);
}